// Round 9
// baseline (53.176 us; speedup 1.0000x reference)
//
#include <hip/hip_runtime.h>

// Problem constants: x (8, 8192, 512) f32, W (512,128) f32, perm (128,) f32
#define B_ 8
#define N_ 8192
#define D_ 512
#define R_ 128
#define CHUNKS_ 64             // chunks per batch; grid = B_*CHUNKS_ = 512
#define ROWS_ 128              // N_/CHUNKS_

typedef float f4_t __attribute__((ext_vector_type(4)));

// Single fused kernel, per-batch producer/consumer flags, NO cache-wide
// maintenance ops (the R4/R5 lesson: agent-scope release/acquire emit
// buffer_wbl2/buffer_inv which thrash the XCD L2 for all resident waves).
// partial_y moves through RELAXED agent-scope atomics (L1/L2-bypass, LLC
// coherent); producer-side ordering comes from the vmcnt(0) drain hipcc
// emits before s_barrier (__syncthreads).
// 512 blocks x 512 threads = 2 blocks/CU, 16/32 waves -> all blocks
// co-resident; per-b spin is deadlock-free by construction.
__global__ __launch_bounds__(512) void k_fused(const float* __restrict__ x,
                                               const float* __restrict__ W,
                                               const float* __restrict__ perm,
                                               float* __restrict__ partial_y,
                                               unsigned int* __restrict__ counter,
                                               float* __restrict__ out) {
    const int b  = blockIdx.x >> 6;         // / CHUNKS_
    const int ck = blockIdx.x & (CHUNKS_ - 1);
    const int t  = threadIdx.x;

    __shared__ float4 s4[512];
    __shared__ float  xs[D_];
    __shared__ float  red[512];
    __shared__ float  yv[R_];

    // ---- Phase 1: stream ROWS_ rows of x, column-sum into xs ----
    const int dq = t & 127;                 // float4 column over d
    const int rp = t >> 7;                  // 0..3 row-parallel groups
    const float4* x4 = reinterpret_cast<const float4*>(x)
                       + ((size_t)b * N_ + (size_t)ck * ROWS_) * (D_ / 4);

    float4 acc = make_float4(0.f, 0.f, 0.f, 0.f);
    #pragma unroll 8
    for (int n = rp; n < ROWS_; n += 4) {
        float4 v = x4[(size_t)n * (D_ / 4) + dq];
        acc.x += v.x; acc.y += v.y; acc.z += v.z; acc.w += v.w;
    }
    s4[t] = acc;
    __syncthreads();
    if (rp == 0) {
        float4 a1 = s4[dq + 128], a2 = s4[dq + 256], a3 = s4[dq + 384];
        float4 r;
        r.x = (acc.x + a1.x) + (a2.x + a3.x);
        r.y = (acc.y + a1.y) + (a2.y + a3.y);
        r.z = (acc.z + a1.z) + (a2.z + a3.z);
        r.w = (acc.w + a1.w) + (a2.w + a3.w);
        reinterpret_cast<float4*>(xs)[dq] = r;
    }
    __syncthreads();

    // ---- project chunk sum through W: 4 groups x 128 channels ----
    const int r = t & 127;
    const int g = t >> 7;                   // 0..3
    float a = 0.f;
    #pragma unroll 8
    for (int d0 = 0; d0 < 128; ++d0) {
        const int d = g * 128 + d0;
        a = fmaf(xs[d], W[(size_t)d * R_ + r], a);
    }
    red[t] = a;
    __syncthreads();
    if (g == 0) {
        float v = (red[r] + red[r + 128]) + (red[r + 256] + red[r + 384]);
        // L2-bypass store, coherent at LLC across XCDs.
        __hip_atomic_store(&partial_y[(size_t)blockIdx.x * R_ + r], v,
                           __ATOMIC_RELAXED, __HIP_MEMORY_SCOPE_AGENT);
    }
    // hipcc drains vmcnt(0) before this barrier -> stores are LLC-visible.
    __syncthreads();

    // ---- signal + per-b spin (relaxed only; no wbl2/inv anywhere) ----
    if (t == 0) {
        __hip_atomic_fetch_add(&counter[b], 1u, __ATOMIC_RELAXED,
                               __HIP_MEMORY_SCOPE_AGENT);
        while (__hip_atomic_load(&counter[b], __ATOMIC_RELAXED,
                                 __HIP_MEMORY_SCOPE_AGENT) < (unsigned)CHUNKS_) {
            __builtin_amdgcn_s_sleep(2);
        }
    }
    __syncthreads();

    // ---- Phase 2: every block redundantly reduces its b's 64 projections ----
    // (32 KB per block from LLC via bypass loads; 16 MB aggregate — cheap)
    const int q4 = t >> 7;                  // 0..3 over chunk quarters
    float s = 0.f;
    #pragma unroll
    for (int c = 0; c < CHUNKS_ / 4; ++c) {
        const size_t idx = ((size_t)b * CHUNKS_ + (size_t)q4 * (CHUNKS_ / 4) + c) * R_ + r;
        s += __hip_atomic_load(&partial_y[idx], __ATOMIC_RELAXED,
                               __HIP_MEMORY_SCOPE_AGENT);
    }
    red[t] = s;
    __syncthreads();
    if (g == 0)
        yv[r] = ((red[r] + red[r + 128]) + (red[r + 256] + red[r + 384]))
                * perm[r] * (1.0f / (float)N_);
    __syncthreads();

    // ---- broadcast-write this block's own ROWS_ output rows ----
    const int q   = t & 31;                 // float4 column 0..31
    const int rp2 = t >> 5;                 // 0..15
    f4_t val;
    {
        float4 v = reinterpret_cast<const float4*>(yv)[q];
        val.x = v.x; val.y = v.y; val.z = v.z; val.w = v.w;
    }
    f4_t* out4 = reinterpret_cast<f4_t*>(out)
                 + ((size_t)b * N_ + (size_t)ck * ROWS_) * (R_ / 4);
    #pragma unroll
    for (int n = rp2; n < ROWS_; n += 16)
        __builtin_nontemporal_store(val, &out4[(size_t)n * (R_ / 4) + q]);
}

extern "C" void kernel_launch(void* const* d_in, const int* in_sizes, int n_in,
                              void* d_out, int out_size, void* d_ws, size_t ws_size,
                              hipStream_t stream) {
    const float* x    = (const float*)d_in[0];
    const float* W    = (const float*)d_in[1];
    const float* perm = (const float*)d_in[2];
    float* out = (float*)d_out;

    unsigned int* counter = (unsigned int*)d_ws;            // 8 x 4 B
    float* partial_y = (float*)((char*)d_ws + 256);         // 256 KB

    hipMemsetAsync(counter, 0, B_ * sizeof(unsigned int), stream);
    k_fused<<<dim3(B_ * CHUNKS_), dim3(512), 0, stream>>>(x, W, perm,
                                                          partial_y, counter, out);
}